// Round 4
// baseline (959.215 us; speedup 1.0000x reference)
//
#include <hip/hip_runtime.h>
#include <stdint.h>
#include <stddef.h>

#define T_SEQ 2048
#define DIM   4096
#define NH    32
#define NKV   8
#define HD    128
#define KVD   (NKV*HD)   // 1024

typedef __attribute__((ext_vector_type(8))) short short8;
typedef __attribute__((ext_vector_type(4))) float floatx4;

static __device__ __forceinline__ float bf2f(short u) {
    union { unsigned int i; float f; } c; c.i = ((unsigned int)(unsigned short)u) << 16; return c.f;
}
static __device__ __forceinline__ short f2bf(float f) {
    union { float f; unsigned int u; } c; c.f = f;
    unsigned int r = c.u + 0x7fff + ((c.u >> 16) & 1);
    return (short)(r >> 16);
}
// load 8 consecutive fp32, round-to-nearest-even to bf16
static __device__ __forceinline__ short8 ld8_f2b(const float* p) {
    floatx4 a = *(const floatx4*)p;
    floatx4 b = *(const floatx4*)(p + 4);
    short8 r;
    r[0]=f2bf(a[0]); r[1]=f2bf(a[1]); r[2]=f2bf(a[2]); r[3]=f2bf(a[3]);
    r[4]=f2bf(b[0]); r[5]=f2bf(b[1]); r[6]=f2bf(b[2]); r[7]=f2bf(b[3]);
    return r;
}

// ---------------------------------------------------------------------------
// C[M,N] = A[M,K] * B[N,K]^T + bias[N].  B always fp32 (weights), bias fp32.
// A_F32: A is fp32 (converted in staging) else bf16.  C_F32: fp32 out else bf16.
// m92/m97 structure: 128x128 tile, BK=32, 4 waves 2x2, 16x16x32 bf16 MFMA.
// ---------------------------------------------------------------------------
template<bool A_F32, bool C_F32>
__global__ __launch_bounds__(256)
void gemm_bt(const void* __restrict__ Ap, const float* __restrict__ Bp,
             const float* __restrict__ bias, void* __restrict__ Cp,
             int M, int N, int K) {
    __shared__ short sA[128*32];
    __shared__ short sB[128*32];
    const int tid  = threadIdx.x;
    const int wave = tid >> 6, lane = tid & 63;
    const int l15  = lane & 15, lq = lane >> 4;
    const int bm   = blockIdx.y * 128, bn = blockIdx.x * 128;
    const int wm   = (wave >> 1) * 64, wn = (wave & 1) * 64;

    floatx4 acc[4][4];
    #pragma unroll
    for (int i = 0; i < 4; i++)
        #pragma unroll
        for (int j = 0; j < 4; j++)
            acc[i][j] = (floatx4)(0.0f);

    const int c0 = tid, c1 = 256 + tid;
    const int r0 = c0 >> 2, k0 = (c0 & 3) * 8;
    const int r1 = c1 >> 2, k1 = (c1 & 3) * 8;
    const float* pB0 = Bp + (size_t)(bn + r0) * K + k0;
    const float* pB1 = Bp + (size_t)(bn + r1) * K + k1;
    const float* pA0f = (const float*)Ap + (size_t)(bm + r0) * K + k0;
    const float* pA1f = (const float*)Ap + (size_t)(bm + r1) * K + k1;
    const short* pA0b = (const short*)Ap + (size_t)(bm + r0) * K + k0;
    const short* pA1b = (const short*)Ap + (size_t)(bm + r1) * K + k1;

    for (int kt = 0; kt < K; kt += 32) {
        __syncthreads();
        if (A_F32) {
            *(short8*)&sA[r0*32 + k0] = ld8_f2b(pA0f + kt);
            *(short8*)&sA[r1*32 + k1] = ld8_f2b(pA1f + kt);
        } else {
            *(short8*)&sA[r0*32 + k0] = *(const short8*)(pA0b + kt);
            *(short8*)&sA[r1*32 + k1] = *(const short8*)(pA1b + kt);
        }
        *(short8*)&sB[r0*32 + k0] = ld8_f2b(pB0 + kt);
        *(short8*)&sB[r1*32 + k1] = ld8_f2b(pB1 + kt);
        __syncthreads();

        short8 af[4], bfr[4];
        #pragma unroll
        for (int mi = 0; mi < 4; mi++)
            af[mi] = *(const short8*)&sA[(wm + mi*16 + l15)*32 + lq*8];
        #pragma unroll
        for (int ni = 0; ni < 4; ni++)
            bfr[ni] = *(const short8*)&sB[(wn + ni*16 + l15)*32 + lq*8];
        #pragma unroll
        for (int mi = 0; mi < 4; mi++)
            #pragma unroll
            for (int ni = 0; ni < 4; ni++)
                acc[mi][ni] = __builtin_amdgcn_mfma_f32_16x16x32_bf16(af[mi], bfr[ni], acc[mi][ni], 0, 0, 0);
    }

    // epilogue: C/D layout col=lane&15, row=(lane>>4)*4+reg  [m89/m91]
    #pragma unroll
    for (int ni = 0; ni < 4; ni++) {
        int col = bn + wn + ni*16 + l15;
        float bv = bias[col];
        #pragma unroll
        for (int mi = 0; mi < 4; mi++) {
            int row = bm + wm + mi*16 + lq*4;
            #pragma unroll
            for (int r = 0; r < 4; r++) {
                float v = acc[mi][ni][r] + bv;
                if (C_F32) ((float*)Cp)[(size_t)(row + r)*N + col] = v;
                else       ((short*)Cp)[(size_t)(row + r)*N + col] = f2bf(v);
            }
        }
    }
}

// ---------------------------------------------------------------------------
// RoPE in-place on bf16 Q (T,NH,HD) and K (T,NKV,HD); freqs are fp32.
// ---------------------------------------------------------------------------
__global__ __launch_bounds__(256)
void rope_k(short* __restrict__ Q, short* __restrict__ Kc,
            const float* __restrict__ fc, const float* __restrict__ fs) {
    int idx = blockIdx.x * 256 + threadIdx.x;
    const int NQ = T_SEQ * NH  * (HD/2);
    const int NK = T_SEQ * NKV * (HD/2);
    short* base; int t, i; size_t off;
    if (idx < NQ) {
        i = idx & 63;
        int th = idx >> 6;       // t*NH + h
        t = th >> 5;             // / NH
        off = (size_t)th * HD + i*2;
        base = Q;
    } else if (idx < NQ + NK) {
        int kidx = idx - NQ;
        i = kidx & 63;
        int th = kidx >> 6;      // t*NKV + kv
        t = th >> 3;             // / NKV
        off = (size_t)th * HD + i*2;
        base = Kc;
    } else return;
    float re = bf2f(base[off]), im = bf2f(base[off+1]);
    float c = fc[t*64 + i], s = fs[t*64 + i];
    base[off]   = f2bf(re*c - im*s);
    base[off+1] = f2bf(re*s + im*c);
}

// ---------------------------------------------------------------------------
// Causal flash attention, bf16 in/out. Grid: (T/64, NH). Block 256 (4 waves).
// Wave w owns q-rows [qb+16w, qb+16w+16). K/V tiles of 64 keys.
// ---------------------------------------------------------------------------
__global__ __launch_bounds__(256)
void flash_attn(const short* __restrict__ Q, const short* __restrict__ Kc,
                const short* __restrict__ Vc, short* __restrict__ O) {
    __shared__ short sQ[64*136];
    __shared__ short sK[64*136];
    __shared__ short sVt[128*64];     // sVt[d][k], chunk-swizzled
    __shared__ short sP[4][16*64];    // per-wave P strip, chunk-swizzled
    const int tid  = threadIdx.x;
    const int wave = tid >> 6, lane = tid & 63;
    const int l15  = lane & 15, lq = lane >> 4;
    const int qt = blockIdx.x, h = blockIdx.y;
    const int kv = h >> 2;            // REP = 4
    const int qb = qt * 64;
    const float scale = 0.08838834764831845f;  // 1/sqrt(128)

    #pragma unroll
    for (int i = 0; i < 4; i++) {
        int c = i*256 + tid;
        int row = c >> 4, co = (c & 15) * 8;
        *(short8*)&sQ[row*136 + co] =
            *(const short8*)(Q + (size_t)(qb + row)*DIM + h*HD + co);
    }

    float m_r[4], l_r[4];
    floatx4 o_acc[8];
    #pragma unroll
    for (int r = 0; r < 4; r++) { m_r[r] = -1e30f; l_r[r] = 0.0f; }
    #pragma unroll
    for (int nd = 0; nd < 8; nd++) o_acc[nd] = (floatx4)(0.0f);

    for (int kt = 0; kt <= qt; kt++) {
        __syncthreads();
        #pragma unroll
        for (int i = 0; i < 4; i++) {
            int c = i*256 + tid;
            int row = c >> 4, co = (c & 15)*8;
            *(short8*)&sK[row*136 + co] =
                *(const short8*)(Kc + (size_t)(kt*64 + row)*KVD + kv*HD + co);
            short8 v = *(const short8*)(Vc + (size_t)(kt*64 + row)*KVD + kv*HD + co);
            #pragma unroll
            for (int j = 0; j < 8; j++) {
                int d = co + j;
                int kc = (row >> 3) ^ ((d + (d >> 3)) & 7);
                sVt[d*64 + kc*8 + (row & 7)] = v[j];
            }
        }
        __syncthreads();

        // S = Q K^T  (wave strip 16x64)
        floatx4 s_acc[4];
        #pragma unroll
        for (int ni = 0; ni < 4; ni++) s_acc[ni] = (floatx4)(0.0f);
        #pragma unroll
        for (int ks = 0; ks < 4; ks++) {
            short8 qf = *(const short8*)&sQ[(wave*16 + l15)*136 + ks*32 + lq*8];
            #pragma unroll
            for (int ni = 0; ni < 4; ni++) {
                short8 kf = *(const short8*)&sK[(ni*16 + l15)*136 + ks*32 + lq*8];
                s_acc[ni] = __builtin_amdgcn_mfma_f32_16x16x32_bf16(qf, kf, s_acc[ni], 0, 0, 0);
            }
        }

        // mask + scale + online softmax (rows lq*4+r)
        float sv[4][4], mx[4], alpha[4], rs[4];
        #pragma unroll
        for (int r = 0; r < 4; r++) mx[r] = -1e30f;
        #pragma unroll
        for (int ni = 0; ni < 4; ni++) {
            int col = kt*64 + ni*16 + l15;
            #pragma unroll
            for (int r = 0; r < 4; r++) {
                int row = qb + wave*16 + lq*4 + r;
                float x = s_acc[ni][r] * scale;
                x = (col <= row) ? x : -1e30f;
                sv[ni][r] = x;
                mx[r] = fmaxf(mx[r], x);
            }
        }
        #pragma unroll
        for (int off = 1; off < 16; off <<= 1) {
            #pragma unroll
            for (int r = 0; r < 4; r++)
                mx[r] = fmaxf(mx[r], __shfl_xor(mx[r], off));
        }
        #pragma unroll
        for (int r = 0; r < 4; r++) {
            float mn = fmaxf(m_r[r], mx[r]);
            alpha[r] = __expf(fminf(m_r[r] - mn, 0.0f));
            m_r[r] = mn;
            rs[r] = 0.0f;
        }
        #pragma unroll
        for (int ni = 0; ni < 4; ni++)
            #pragma unroll
            for (int r = 0; r < 4; r++) {
                float p = __expf(fminf(sv[ni][r] - m_r[r], 0.0f));
                sv[ni][r] = p;
                rs[r] += p;
            }
        #pragma unroll
        for (int off = 1; off < 16; off <<= 1) {
            #pragma unroll
            for (int r = 0; r < 4; r++)
                rs[r] += __shfl_xor(rs[r], off);
        }
        #pragma unroll
        for (int r = 0; r < 4; r++) l_r[r] = alpha[r]*l_r[r] + rs[r];

        // P strip -> LDS (C layout -> A layout), swizzled
        #pragma unroll
        for (int ni = 0; ni < 4; ni++)
            #pragma unroll
            for (int r = 0; r < 4; r++) {
                int q = lq*4 + r, k = ni*16 + l15;
                int kc = (k >> 3) ^ (q & 7);
                sP[wave][q*64 + kc*8 + (k & 7)] = f2bf(sv[ni][r]);
            }
        #pragma unroll
        for (int nd = 0; nd < 8; nd++)
            #pragma unroll
            for (int r = 0; r < 4; r++) o_acc[nd][r] *= alpha[r];
        __syncthreads();

        // O += P V   (64 keys, 2 k-steps)
        #pragma unroll
        for (int ks = 0; ks < 2; ks++) {
            int kk = ks*32 + lq*8;
            int q  = l15;
            short8 pf = *(const short8*)&sP[wave][q*64 + (((kk >> 3) ^ (q & 7))*8)];
            #pragma unroll
            for (int nd = 0; nd < 8; nd++) {
                int d = nd*16 + l15;
                short8 vf = *(const short8*)&sVt[d*64 + (((kk >> 3) ^ ((d + (d >> 3)) & 7))*8)];
                o_acc[nd] = __builtin_amdgcn_mfma_f32_16x16x32_bf16(pf, vf, o_acc[nd], 0, 0, 0);
            }
        }
    }

    #pragma unroll
    for (int nd = 0; nd < 8; nd++) {
        int col = h*HD + nd*16 + l15;
        #pragma unroll
        for (int r = 0; r < 4; r++) {
            int row = qb + wave*16 + lq*4 + r;
            O[(size_t)row*DIM + col] = f2bf(o_acc[nd][r] / l_r[r]);
        }
    }
}

// ---------------------------------------------------------------------------
extern "C" void kernel_launch(void* const* d_in, const int* in_sizes, int n_in,
                              void* d_out, int out_size, void* d_ws, size_t ws_size,
                              hipStream_t stream) {
    const float* x    = (const float*)d_in[0];
    const float* fc   = (const float*)d_in[1];
    const float* fs   = (const float*)d_in[2];
    // d_in[3] mask: causal, analytic. d_in[4,5] caches: dead (pos=0). d_in[12]=pos.
    const float* wk_w = (const float*)d_in[6];
    const float* wk_b = (const float*)d_in[7];
    const float* wv_w = (const float*)d_in[8];
    const float* wv_b = (const float*)d_in[9];
    const float* wo_w = (const float*)d_in[10];
    const float* wo_b = (const float*)d_in[11];
    float* out = (float*)d_out;

    short* Q  = (short*)d_ws;                       // 2048*4096 bf16
    short* K  = Q  + (size_t)T_SEQ * DIM;           // 2048*1024 bf16
    short* V  = K  + (size_t)T_SEQ * KVD;           // 2048*1024 bf16
    short* AO = V  + (size_t)T_SEQ * KVD;           // 2048*4096 bf16

    dim3 blk(256);
    // reference quirk: q is projected with wo_w/wo_b
    gemm_bt<true,false><<<dim3(DIM/128, T_SEQ/128), blk, 0, stream>>>(x, wo_w, wo_b, Q, T_SEQ, DIM, DIM);
    gemm_bt<true,false><<<dim3(KVD/128, T_SEQ/128), blk, 0, stream>>>(x, wk_w, wk_b, K, T_SEQ, KVD, DIM);
    gemm_bt<true,false><<<dim3(KVD/128, T_SEQ/128), blk, 0, stream>>>(x, wv_w, wv_b, V, T_SEQ, KVD, DIM);

    int nrope = T_SEQ*NH*(HD/2) + T_SEQ*NKV*(HD/2);
    rope_k<<<dim3((nrope + 255)/256), blk, 0, stream>>>(Q, K, fc, fs);

    flash_attn<<<dim3(T_SEQ/64, NH), blk, 0, stream>>>(Q, K, V, AO);

    gemm_bt<false,true><<<dim3(DIM/128, T_SEQ/128), blk, 0, stream>>>(AO, wo_w, wo_b, out, T_SEQ, DIM, DIM);
}

// Round 5
// 642.819 us; speedup vs baseline: 1.4922x; 1.4922x over previous
//
#include <hip/hip_runtime.h>
#include <stdint.h>
#include <stddef.h>

#define T_SEQ 2048
#define DIM   4096
#define NH    32
#define NKV   8
#define HD    128
#define KVD   (NKV*HD)   // 1024

typedef __attribute__((ext_vector_type(8))) short short8;
typedef __attribute__((ext_vector_type(4))) float floatx4;

static __device__ __forceinline__ float bf2f(short u) {
    union { unsigned int i; float f; } c; c.i = ((unsigned int)(unsigned short)u) << 16; return c.f;
}
static __device__ __forceinline__ short f2bf(float f) {
    union { float f; unsigned int u; } c; c.f = f;
    unsigned int r = c.u + 0x7fff + ((c.u >> 16) & 1);
    return (short)(r >> 16);
}
static __device__ __forceinline__ short8 ld8_f2b(const float* p) {
    floatx4 a = *(const floatx4*)p;
    floatx4 b = *(const floatx4*)(p + 4);
    short8 r;
    r[0]=f2bf(a[0]); r[1]=f2bf(a[1]); r[2]=f2bf(a[2]); r[3]=f2bf(a[3]);
    r[4]=f2bf(b[0]); r[5]=f2bf(b[1]); r[6]=f2bf(b[2]); r[7]=f2bf(b[3]);
    return r;
}

// async 16B global->LDS (m97 pattern; LDS dest is wave-uniform-base + lane*16)
#define GLD16(g, l) __builtin_amdgcn_global_load_lds( \
    (const __attribute__((address_space(1))) unsigned int*)(g), \
    (__attribute__((address_space(3))) unsigned int*)(l), 16, 0, 0)

// ---------------------------------------------------------------------------
// fp32 -> bf16 bulk convert: x (8M), wk (4M), wv (4M), wo (16M); 8 elems/thread
// ---------------------------------------------------------------------------
__global__ __launch_bounds__(256)
void cvt_bf16(const float* __restrict__ x, const float* __restrict__ wk,
              const float* __restrict__ wv, const float* __restrict__ wo,
              short* __restrict__ xb, short* __restrict__ wkb,
              short* __restrict__ wvb, short* __restrict__ wob) {
    size_t i8 = ((size_t)blockIdx.x * 256 + threadIdx.x) * 8;
    const float* src; short* dst; size_t off;
    if (i8 < 8388608)        { src = x;  dst = xb;  off = i8; }
    else if (i8 < 12582912)  { src = wk; dst = wkb; off = i8 - 8388608; }
    else if (i8 < 16777216)  { src = wv; dst = wvb; off = i8 - 12582912; }
    else                     { src = wo; dst = wob; off = i8 - 16777216; }
    *(short8*)(dst + off) = ld8_f2b(src + off);
}

// ---------------------------------------------------------------------------
// m97-style GEMM core: C[M,N] = A[M,K]*B[N,K]^T + bias. bf16 A/B via
// global_load_lds dwordx4; 128x128 tile, BK=32, 4 waves 2x2; fp32 bias.
// ---------------------------------------------------------------------------
template<bool C_F32>
static __device__ __forceinline__
void gemm_core(const short* __restrict__ A, const short* __restrict__ B,
               const float* __restrict__ bias, void* __restrict__ Cp,
               int N, int K, int bm, int bn) {
    __shared__ short sA[128*32];
    __shared__ short sB[128*32];
    const int tid  = threadIdx.x;
    const int wave = tid >> 6, lane = tid & 63;
    const int l15  = lane & 15, lq = lane >> 4;
    const int wm   = (wave >> 1) * 64, wn = (wave & 1) * 64;

    floatx4 acc[4][4];
    #pragma unroll
    for (int i = 0; i < 4; i++)
        #pragma unroll
        for (int j = 0; j < 4; j++)
            acc[i][j] = (floatx4)(0.0f);

    // staging map: chunk c -> lds elem c*8 (lane-linear, 16B/lane)
    const int c0 = tid, c1 = 256 + tid;
    const int r0 = c0 >> 2, k0 = (c0 & 3) * 8;
    const int r1 = c1 >> 2, k1 = (c1 & 3) * 8;
    const short* pA0 = A + (size_t)(bm + r0) * K + k0;
    const short* pA1 = A + (size_t)(bm + r1) * K + k1;
    const short* pB0 = B + (size_t)(bn + r0) * K + k0;
    const short* pB1 = B + (size_t)(bn + r1) * K + k1;

    for (int kt = 0; kt < K; kt += 32) {
        __syncthreads();
        GLD16(pA0 + kt, &sA[c0 * 8]);
        GLD16(pA1 + kt, &sA[c1 * 8]);
        GLD16(pB0 + kt, &sB[c0 * 8]);
        GLD16(pB1 + kt, &sB[c1 * 8]);
        __syncthreads();   // drains vmcnt before barrier

        short8 af[4], bfr[4];
        #pragma unroll
        for (int mi = 0; mi < 4; mi++)
            af[mi] = *(const short8*)&sA[(wm + mi*16 + l15)*32 + lq*8];
        #pragma unroll
        for (int ni = 0; ni < 4; ni++)
            bfr[ni] = *(const short8*)&sB[(wn + ni*16 + l15)*32 + lq*8];
        #pragma unroll
        for (int mi = 0; mi < 4; mi++)
            #pragma unroll
            for (int ni = 0; ni < 4; ni++)
                acc[mi][ni] = __builtin_amdgcn_mfma_f32_16x16x32_bf16(af[mi], bfr[ni], acc[mi][ni], 0, 0, 0);
    }

    // epilogue: C/D layout col=lane&15, row=(lane>>4)*4+reg  [m89/m91]
    #pragma unroll
    for (int ni = 0; ni < 4; ni++) {
        int col = bn + wn + ni*16 + l15;
        float bv = bias[col];
        #pragma unroll
        for (int mi = 0; mi < 4; mi++) {
            int row = bm + wm + mi*16 + lq*4;
            #pragma unroll
            for (int r = 0; r < 4; r++) {
                float v = acc[mi][ni][r] + bv;
                if (C_F32) ((float*)Cp)[(size_t)(row + r)*N + col] = v;
                else       ((short*)Cp)[(size_t)(row + r)*N + col] = f2bf(v);
            }
        }
    }
}

template<bool C_F32>
__global__ __launch_bounds__(256)
void gemm_bt(const short* __restrict__ A, const short* __restrict__ B,
             const float* __restrict__ bias, void* __restrict__ Cp,
             int N, int K) {
    gemm_core<C_F32>(A, B, bias, Cp, N, K, blockIdx.y * 128, blockIdx.x * 128);
}

// K and V projections fused into one dispatch (z selects), 256 blocks total
__global__ __launch_bounds__(256)
void gemm_kv(const short* __restrict__ A,
             const short* __restrict__ Bk, const float* __restrict__ bk, short* __restrict__ Ck,
             const short* __restrict__ Bv, const float* __restrict__ bv, short* __restrict__ Cv) {
    const short* B = blockIdx.z ? Bv : Bk;
    const float* bias = blockIdx.z ? bv : bk;
    short* C = blockIdx.z ? Cv : Ck;
    gemm_core<false>(A, B, bias, C, KVD, DIM, blockIdx.y * 128, blockIdx.x * 128);
}

// ---------------------------------------------------------------------------
// RoPE in-place on bf16 Q (T,NH,HD) and K (T,NKV,HD); freqs fp32
// ---------------------------------------------------------------------------
__global__ __launch_bounds__(256)
void rope_k(short* __restrict__ Q, short* __restrict__ Kc,
            const float* __restrict__ fc, const float* __restrict__ fs) {
    int idx = blockIdx.x * 256 + threadIdx.x;
    const int NQ = T_SEQ * NH  * (HD/2);
    const int NK = T_SEQ * NKV * (HD/2);
    short* base; int t, i; size_t off;
    if (idx < NQ) {
        i = idx & 63;
        int th = idx >> 6;
        t = th >> 5;
        off = (size_t)th * HD + i*2;
        base = Q;
    } else if (idx < NQ + NK) {
        int kidx = idx - NQ;
        i = kidx & 63;
        int th = kidx >> 6;
        t = th >> 3;
        off = (size_t)th * HD + i*2;
        base = Kc;
    } else return;
    float re = bf2f(base[off]), im = bf2f(base[off+1]);
    float c = fc[t*64 + i], s = fs[t*64 + i];
    base[off]   = f2bf(re*c - im*s);
    base[off+1] = f2bf(re*s + im*c);
}

// ---------------------------------------------------------------------------
// V[T,KVD] -> Vt[KVD,T]  (64x64 LDS tiles)
// ---------------------------------------------------------------------------
__global__ __launch_bounds__(256)
void vtrans(const short* __restrict__ V, short* __restrict__ Vt) {
    __shared__ short sT[64*72];
    const int tid = threadIdx.x;
    const int bt = blockIdx.x, bd = blockIdx.y;
    #pragma unroll
    for (int i = 0; i < 2; i++) {
        int c = i*256 + tid;
        int r = c >> 3, c8 = (c & 7) * 8;
        *(short8*)&sT[r*72 + c8] = *(const short8*)(V + (size_t)(bt*64 + r)*KVD + bd*64 + c8);
    }
    __syncthreads();
    #pragma unroll
    for (int i = 0; i < 2; i++) {
        int c = i*256 + tid;
        int d = c >> 3, t8 = (c & 7) * 8;
        short8 o;
        #pragma unroll
        for (int j = 0; j < 8; j++) o[j] = sT[(t8 + j)*72 + d];
        *(short8*)(Vt + (size_t)(bd*64 + d)*T_SEQ + bt*64 + t8) = o;
    }
}

// ---------------------------------------------------------------------------
// Causal flash attention, kv-grouped: grid (T/64, NKV), block 512 (8 waves).
// Block = (64 q-rows) x (4 heads of one kv group). Wave w: head=w>>1,
// q-half=(w&1)*32, 32 q-rows (mi=2). Q frags hoisted to regs; sQ reused as sP.
// V read from pre-transposed Vt (b128 staging, no scatter).
// ---------------------------------------------------------------------------
#define ROWQ 520
#define ROWK 136
#define ROWV 72

__global__ __launch_bounds__(512, 2)
void flash_attn(const short* __restrict__ Q, const short* __restrict__ Kc,
                const short* __restrict__ Vt, short* __restrict__ O) {
    __shared__ short sQ[64*ROWQ];     // staging for Q; reused as sP strips
    __shared__ short sK[64*ROWK];
    __shared__ short sV[128*ROWV];    // sV[d][k]
    const int tid  = threadIdx.x;
    const int wave = tid >> 6, lane = tid & 63;
    const int l15  = lane & 15, lq = lane >> 4;
    const int qt = blockIdx.x, kvg = blockIdx.y;
    const int hl = wave >> 1;            // head_local 0..3
    const int qh = (wave & 1) * 32;      // q half offset
    const int qb = qt * 64;
    const float scale = 0.08838834764831845f;  // 1/sqrt(128)

    // stage Q slice: rows qb..qb+64, cols kvg*512..+512 (4 heads contiguous)
    #pragma unroll
    for (int i = 0; i < 8; i++) {
        int c = i*512 + tid;
        int q = c >> 6, hd8 = (c & 63) * 8;
        *(short8*)&sQ[q*ROWQ + hd8] =
            *(const short8*)(Q + (size_t)(qb + q)*DIM + kvg*512 + hd8);
    }
    __syncthreads();
    // hoist Q fragments: wave's 32 q-rows x 128 d -> 32 VGPRs bf16
    short8 qf[2][4];
    #pragma unroll
    for (int mi = 0; mi < 2; mi++)
        #pragma unroll
        for (int ks = 0; ks < 4; ks++)
            qf[mi][ks] = *(const short8*)&sQ[(qh + mi*16 + l15)*ROWQ + hl*128 + ks*32 + lq*8];

    short* sP = sQ + wave*2048;   // per-wave 32x64 strip (fits: 8*2048 <= 64*520)

    float m_r[2][4], l_r[2][4];
    floatx4 o_acc[2][8];
    #pragma unroll
    for (int mi = 0; mi < 2; mi++) {
        #pragma unroll
        for (int r = 0; r < 4; r++) { m_r[mi][r] = -1e30f; l_r[mi][r] = 0.0f; }
        #pragma unroll
        for (int nd = 0; nd < 8; nd++) o_acc[mi][nd] = (floatx4)(0.0f);
    }

    for (int kt = 0; kt <= qt; kt++) {
        __syncthreads();   // prev-iter frag reads done (and Q hoist on iter 0)
        // stage K (row-major) and V^T (row-major from Vt) — b128, no scatter
        #pragma unroll
        for (int i = 0; i < 2; i++) {
            int c = i*512 + tid;
            int r = c >> 4, c8 = (c & 15) * 8;
            *(short8*)&sK[r*ROWK + c8] =
                *(const short8*)(Kc + (size_t)(kt*64 + r)*KVD + kvg*HD + c8);
            int rv = c >> 3, v8 = (c & 7) * 8;
            *(short8*)&sV[rv*ROWV + v8] =
                *(const short8*)(Vt + (size_t)(kvg*HD + rv)*T_SEQ + kt*64 + v8);
        }
        __syncthreads();

        // S = Q K^T: 32q x 64k, K=128 (kf read shared across mi)
        floatx4 s_acc[2][4];
        #pragma unroll
        for (int mi = 0; mi < 2; mi++)
            #pragma unroll
            for (int ni = 0; ni < 4; ni++) s_acc[mi][ni] = (floatx4)(0.0f);
        #pragma unroll
        for (int ks = 0; ks < 4; ks++)
            #pragma unroll
            for (int ni = 0; ni < 4; ni++) {
                short8 kf = *(const short8*)&sK[(ni*16 + l15)*ROWK + ks*32 + lq*8];
                s_acc[0][ni] = __builtin_amdgcn_mfma_f32_16x16x32_bf16(qf[0][ks], kf, s_acc[0][ni], 0, 0, 0);
                s_acc[1][ni] = __builtin_amdgcn_mfma_f32_16x16x32_bf16(qf[1][ks], kf, s_acc[1][ni], 0, 0, 0);
            }

        // mask + scale + online softmax; C-layout rows = lq*4+r, cols = l15
        #pragma unroll
        for (int mi = 0; mi < 2; mi++) {
            float sv[4][4], mx[4], alpha[4], rs[4];
            #pragma unroll
            for (int r = 0; r < 4; r++) mx[r] = -1e30f;
            #pragma unroll
            for (int ni = 0; ni < 4; ni++) {
                int col = kt*64 + ni*16 + l15;
                #pragma unroll
                for (int r = 0; r < 4; r++) {
                    int row = qb + qh + mi*16 + lq*4 + r;
                    float x = s_acc[mi][ni][r] * scale;
                    x = (col <= row) ? x : -1e30f;
                    sv[ni][r] = x;
                    mx[r] = fmaxf(mx[r], x);
                }
            }
            #pragma unroll
            for (int off = 1; off < 16; off <<= 1)
                #pragma unroll
                for (int r = 0; r < 4; r++)
                    mx[r] = fmaxf(mx[r], __shfl_xor(mx[r], off));
            #pragma unroll
            for (int r = 0; r < 4; r++) {
                float mn = fmaxf(m_r[mi][r], mx[r]);
                alpha[r] = __expf(fminf(m_r[mi][r] - mn, 0.0f));
                m_r[mi][r] = mn;
                rs[r] = 0.0f;
            }
            #pragma unroll
            for (int ni = 0; ni < 4; ni++)
                #pragma unroll
                for (int r = 0; r < 4; r++) {
                    float p = __expf(fminf(sv[ni][r] - m_r[mi][r], 0.0f));
                    sv[ni][r] = p;
                    rs[r] += p;
                }
            #pragma unroll
            for (int off = 1; off < 16; off <<= 1)
                #pragma unroll
                for (int r = 0; r < 4; r++)
                    rs[r] += __shfl_xor(rs[r], off);
            #pragma unroll
            for (int r = 0; r < 4; r++) l_r[mi][r] = alpha[r]*l_r[mi][r] + rs[r];

            // P strip -> own-wave LDS (C->A layout), chunk-XOR swizzle
            #pragma unroll
            for (int ni = 0; ni < 4; ni++)
                #pragma unroll
                for (int r = 0; r < 4; r++) {
                    int q = mi*16 + lq*4 + r, k = ni*16 + l15;
                    sP[q*64 + (((k >> 3) ^ (q & 7))*8) + (k & 7)] = f2bf(sv[ni][r]);
                }
            // rescale O accumulator
            #pragma unroll
            for (int nd = 0; nd < 8; nd++)
                #pragma unroll
                for (int r = 0; r < 4; r++) o_acc[mi][nd][r] *= alpha[r];
        }
        // no barrier: sP strip is wave-private (lgkmcnt ordering within wave)

        // O += P V (contraction over 64 keys; vf read shared across mi)
        #pragma unroll
        for (int ks = 0; ks < 2; ks++) {
            int kk = ks*32 + lq*8;
            short8 pf[2];
            #pragma unroll
            for (int mi = 0; mi < 2; mi++) {
                int q = mi*16 + l15;
                pf[mi] = *(const short8*)&sP[q*64 + (((kk >> 3) ^ (q & 7))*8)];
            }
            #pragma unroll
            for (int nd = 0; nd < 8; nd++) {
                short8 vf = *(const short8*)&sV[(nd*16 + l15)*ROWV + kk];
                o_acc[0][nd] = __builtin_amdgcn_mfma_f32_16x16x32_bf16(pf[0], vf, o_acc[0][nd], 0, 0, 0);
                o_acc[1][nd] = __builtin_amdgcn_mfma_f32_16x16x32_bf16(pf[1], vf, o_acc[1][nd], 0, 0, 0);
            }
        }
    }

    // epilogue
    #pragma unroll
    for (int mi = 0; mi < 2; mi++)
        #pragma unroll
        for (int nd = 0; nd < 8; nd++) {
            int col = (kvg*4 + hl)*HD + nd*16 + l15;
            #pragma unroll
            for (int r = 0; r < 4; r++) {
                int row = qb + qh + mi*16 + lq*4 + r;
                O[(size_t)row*DIM + col] = f2bf(o_acc[mi][nd][r] / l_r[mi][r]);
            }
        }
}

// ---------------------------------------------------------------------------
extern "C" void kernel_launch(void* const* d_in, const int* in_sizes, int n_in,
                              void* d_out, int out_size, void* d_ws, size_t ws_size,
                              hipStream_t stream) {
    const float* x    = (const float*)d_in[0];
    const float* fc   = (const float*)d_in[1];
    const float* fs   = (const float*)d_in[2];
    // d_in[3] mask: causal, analytic. d_in[4,5] caches: dead (pos=0).
    const float* wk_w = (const float*)d_in[6];
    const float* wk_b = (const float*)d_in[7];
    const float* wv_w = (const float*)d_in[8];
    const float* wv_b = (const float*)d_in[9];
    const float* wo_w = (const float*)d_in[10];
    const float* wo_b = (const float*)d_in[11];
    float* out = (float*)d_out;

    short* xb  = (short*)d_ws;                 //  8388608
    short* wkb = xb  + 8388608;                //  4194304
    short* wvb = wkb + 4194304;                //  4194304
    short* wob = wvb + 4194304;                // 16777216
    short* Q   = wob + 16777216;               //  8388608
    short* K   = Q   + 8388608;                //  2097152
    short* V   = K   + 2097152;                //  2097152
    short* Vt  = V   + 2097152;                //  2097152
    short* AO  = Vt  + 2097152;                //  8388608  (total ~113.4 MB)

    cvt_bf16<<<dim3(16384), dim3(256), 0, stream>>>(x, wk_w, wv_w, wo_w, xb, wkb, wvb, wob);

    // reference quirk: q is projected with wo_w/wo_b
    gemm_bt<false><<<dim3(32, 16), dim3(256), 0, stream>>>(xb, wob, wo_b, Q, DIM, DIM);
    gemm_kv<<<dim3(8, 16, 2), dim3(256), 0, stream>>>(xb, wkb, wk_b, K, wvb, wv_b, V);

    int nrope = T_SEQ*NH*(HD/2) + T_SEQ*NKV*(HD/2);
    rope_k<<<dim3((nrope + 255)/256), dim3(256), 0, stream>>>(Q, K, fc, fs);

    vtrans<<<dim3(32, 16), dim3(256), 0, stream>>>(V, Vt);

    flash_attn<<<dim3(32, 8), dim3(512), 0, stream>>>(Q, K, Vt, AO);

    gemm_bt<true><<<dim3(32, 16), dim3(256), 0, stream>>>(AO, wob, wo_b, out, DIM, DIM);
}